// Round 1
// baseline (3494.973 us; speedup 1.0000x reference)
//
#include <hip/hip_runtime.h>
#include <hip/hip_bf16.h>
#include <math.h>

// Problem constants
#define B_   32
#define S_   512
#define V_   30000
#define E_   300
#define H_   200
#define NH_  4
#define ENC_ 400
#define G4_  800     // 4*H
#define NEGV  (-1e9f)
#define SCALE_ 1000.0f

// ---- workspace layout (float offsets) ---- total 33,272,384 floats = ~127 MiB
#define OF_WTF   0ull          // W_hh_f^T  [200][800]
#define OF_WTB   160000ull     // W_hh_b^T  [200][800]
#define OF_QVEC  320000ull     // q_state @ W_q  [400]
#define OF_WKQ   320448ull     // wkq [400][4]
#define OF_THETA 322048ull     // scores [B][4][512]
#define OF_MU    387584ull     // mu     [B][4][512]
#define OF_HP    453120ull     // hp [B][4][400]
#define OF_LEN   504320ull     // lengths (int) [32]
#define OF_XWF   504384ull     // xW forward  [B*S][800]
#define OF_XWB   13611584ull   // xW backward (natural s order) [B*S][800]
#define OF_HF    26718784ull   // h_f [B*S][200]
#define OF_HB    29995584ull   // h_b [B*S][200]

// -------- lengths from mask (dtype auto-detect: u8 / i32 / i64) --------
__global__ void k_lengths(const void* __restrict__ mask, int* __restrict__ lengths) {
  int b = blockIdx.x, lane = threadIdx.x;
  const unsigned char* mb = (const unsigned char*)mask;
  // mask[0,1] is always true (len>=256). u8: byte1==1. i32: byte1==0, word1==1. i64: word1==0.
  int mode;
  if (mb[1] != 0) mode = 0;
  else if (((const int*)mask)[1] != 0) mode = 1;
  else mode = 2;
  int cnt = 0;
  for (int s = lane; s < S_; s += 64) {
    int v;
    if (mode == 0)      v = mb[b*S_ + s] ? 1 : 0;
    else if (mode == 1) v = ((const int*)mask)[b*S_ + s] ? 1 : 0;
    else                v = ((const long long*)mask)[b*S_ + s] ? 1 : 0;
    cnt += v;
  }
  for (int off = 32; off; off >>= 1) cnt += __shfl_xor(cnt, off);
  if (lane == 0) lengths[b] = cnt;
}

// -------- transpose W_hh [800,200] -> WT [200,800] (both dirs) --------
__global__ void k_transpose(const float* __restrict__ Wf, const float* __restrict__ Wb,
                            float* __restrict__ WTf, float* __restrict__ WTb) {
  __shared__ float tile[64][65];
  int bi = blockIdx.x;
  int m = bi / 52, rem = bi % 52;
  int tr = rem / 4, tc = rem % 4;            // 13 row tiles x 4 col tiles
  const float* src = m ? Wb : Wf;
  float* dst = m ? WTb : WTf;
  int t = threadIdx.x;
  int lx = t & 63, ly = t >> 6;
  int r0 = tr*64, k0 = tc*64;
  #pragma unroll
  for (int i = 0; i < 16; ++i) {
    int r = r0 + ly*16 + i, k = k0 + lx;
    if (r < G4_ && k < H_) tile[lx][ly*16+i] = src[(size_t)r*H_ + k];
  }
  __syncthreads();
  #pragma unroll
  for (int i = 0; i < 16; ++i) {
    int k = k0 + ly*16 + i, r = r0 + lx;
    if (r < G4_ && k < H_) dst[(size_t)k*G4_ + r] = tile[ly*16+i][lx];
  }
}

// -------- qvec = q_state @ W_q --------
__global__ void k_qvec(const float* __restrict__ qs, const float* __restrict__ Wq,
                       float* __restrict__ qvec) {
  __shared__ float qsl[ENC_];
  int t = threadIdx.x;
  if (t < ENC_) qsl[t] = qs[t];
  __syncthreads();
  if (t < ENC_) {
    float acc = 0.f;
    for (int i = 0; i < ENC_; ++i) acc += qsl[i] * Wq[(size_t)i*ENC_ + t];
    qvec[t] = acc;
  }
}

// -------- wkq[e][head] = sum_d W_k[e, head*100+d] * qvec[head*100+d] --------
__global__ void k_wkq(const float* __restrict__ Wk, const float* __restrict__ qvec,
                      float* __restrict__ wkq) {
  int t = threadIdx.x;
  int e = blockIdx.x*64 + (t >> 2);
  int head = t & 3;
  if (e < ENC_) {
    float acc = 0.f;
    const float* row = Wk + (size_t)e*ENC_ + head*100;
    const float* qv  = qvec + head*100;
    for (int d = 0; d < 100; ++d) acc += row[d]*qv[d];
    wkq[e*4 + head] = acc;
  }
}

// -------- input projections: gather(embed) @ [w_ih_f | w_ih_b]^T + bias --------
// C rows = 16384 tokens, cols = 1600 (800 fwd | 800 bwd). Tile 128x64, 256 thr, 8x4 micro.
__global__ __launch_bounds__(256) void k_gemm_in(
    const int* __restrict__ x, const float* __restrict__ emb,
    const float* __restrict__ wf, const float* __restrict__ wb,
    const float* __restrict__ bf, const float* __restrict__ bb,
    float* __restrict__ xWf, float* __restrict__ xWb)
{
  __shared__ int xid[128];
  __shared__ __align__(16) float sA[16][128];
  __shared__ __align__(16) float sB[16][64];
  const int t = threadIdx.x;
  const int row0 = blockIdx.x * 128;
  const int col0 = blockIdx.y * 64;
  if (t < 128) xid[t] = x[row0 + t];
  __syncthreads();
  float acc[8][4];
  #pragma unroll
  for (int i = 0; i < 8; ++i)
    #pragma unroll
    for (int j = 0; j < 4; ++j) acc[i][j] = 0.f;
  const int y = t >> 4, xq = t & 15;        // compute micro-tile coords
  const int rl = t >> 1, half = t & 1;      // A staging
  const int cb = t & 63, kq = t >> 6;       // B staging
  const int colg_b = col0 + cb;
  const float* wsrc = (colg_b < 800) ? (wf + (size_t)colg_b*300)
                                     : (wb + (size_t)(colg_b-800)*300);
  const float* asrc = emb + (size_t)xid[rl]*300;
  for (int kc = 0; kc < 19; ++kc) {
    const int k0 = kc*16;
    { // stage A (gathered embedding rows), k-major for b128 frag reads
      const int kb = k0 + half*8;
      const float* src = asrc + kb;
      if (kb + 7 < 300) {
        float4 a  = *(const float4*)(src);
        float4 b4 = *(const float4*)(src+4);
        sA[half*8+0][rl]=a.x;  sA[half*8+1][rl]=a.y;  sA[half*8+2][rl]=a.z;  sA[half*8+3][rl]=a.w;
        sA[half*8+4][rl]=b4.x; sA[half*8+5][rl]=b4.y; sA[half*8+6][rl]=b4.z; sA[half*8+7][rl]=b4.w;
      } else {
        #pragma unroll
        for (int i = 0; i < 8; ++i) sA[half*8+i][rl] = (kb+i < 300) ? src[i] : 0.f;
      }
    }
    { // stage B (weight columns)
      const int kb = k0 + kq*4;
      if (kb + 3 < 300) {
        float4 w4 = *(const float4*)(wsrc + kb);
        sB[kq*4+0][cb]=w4.x; sB[kq*4+1][cb]=w4.y; sB[kq*4+2][cb]=w4.z; sB[kq*4+3][cb]=w4.w;
      } else {
        #pragma unroll
        for (int i = 0; i < 4; ++i) sB[kq*4+i][cb] = (kb+i < 300) ? wsrc[kb+i] : 0.f;
      }
    }
    __syncthreads();
    #pragma unroll
    for (int k = 0; k < 16; ++k) {
      float4 a0 = *(const float4*)&sA[k][y*8];
      float4 a1 = *(const float4*)&sA[k][y*8+4];
      float4 b4 = *(const float4*)&sB[k][xq*4];
      float av[8] = {a0.x,a0.y,a0.z,a0.w,a1.x,a1.y,a1.z,a1.w};
      float bv[4] = {b4.x,b4.y,b4.z,b4.w};
      #pragma unroll
      for (int i = 0; i < 8; ++i)
        #pragma unroll
        for (int j = 0; j < 4; ++j) acc[i][j] += av[i]*bv[j];
    }
    __syncthreads();
  }
  const int colg = col0 + xq*4;
  const bool isF = (colg < 800);
  const int colo = isF ? colg : (colg - 800);
  float4 bias = isF ? *(const float4*)(bf + colo) : *(const float4*)(bb + colo);
  float* dst = isF ? xWf : xWb;
  #pragma unroll
  for (int i = 0; i < 8; ++i) {
    int row = row0 + y*8 + i;
    float4 o = {acc[i][0]+bias.x, acc[i][1]+bias.y, acc[i][2]+bias.z, acc[i][3]+bias.w};
    *(float4*)(dst + (size_t)row*800 + colo) = o;
  }
}

// -------- bidirectional masked LSTM: one WG per (dir, sample) chain --------
// Weights WT [200][800] streamed from L2 each step (1.28MB shared by all 64 WGs).
// Threads t<1000: (kk = t/200) k-slice of 40, (q = t%200) row quad 4q..4q+3.
// Threads t<200 additionally do the per-hidden-unit elementwise (c in registers).
__global__ __launch_bounds__(1024) void k_lstm(
    const float* __restrict__ xWf, const float* __restrict__ xWb,
    const float* __restrict__ WTf, const float* __restrict__ WTb,
    const int* __restrict__ lengths,
    float* __restrict__ h_f, float* __restrict__ h_b)
{
  const int wg = blockIdx.x;
  const int dir = wg >> 5;
  const int b = wg & 31;
  const float* __restrict__ xW  = dir ? xWb : xWf;
  const float* __restrict__ WT  = dir ? WTb : WTf;
  float* __restrict__ hout      = dir ? h_b : h_f;
  const int len = lengths[b];
  __shared__ __align__(16) float sh[H_];
  __shared__ __align__(16) float gp[5][G4_];
  const int t = threadIdx.x;
  const int kk = (t < 1000) ? (t / 200) : -1;
  const int q  = (t < 1000) ? (t % 200) : 0;
  float c_j = 0.f;
  if (t < H_) sh[t] = 0.f;
  __syncthreads();
  const float* wbase = WT + (size_t)(kk < 0 ? 0 : kk)*40*G4_ + q*4;
  for (int step = 0; step < len; ++step) {
    if (kk >= 0) {
      float ax=0.f, ay=0.f, az=0.f, aw=0.f;
      float4 xw4 = {0.f,0.f,0.f,0.f};
      if (kk == 0) {
        int pos = dir ? (len-1-step) : step;   // backward consumes reversed rows
        xw4 = *(const float4*)(xW + ((size_t)b*S_ + pos)*G4_ + q*4);
      }
      #pragma unroll
      for (int k4 = 0; k4 < 10; ++k4) {
        float4 h4 = *(const float4*)&sh[kk*40 + k4*4];
        float4 w0 = *(const float4*)(wbase + (size_t)(k4*4+0)*G4_);
        float4 w1 = *(const float4*)(wbase + (size_t)(k4*4+1)*G4_);
        float4 w2 = *(const float4*)(wbase + (size_t)(k4*4+2)*G4_);
        float4 w3 = *(const float4*)(wbase + (size_t)(k4*4+3)*G4_);
        ax += h4.x*w0.x + h4.y*w1.x + h4.z*w2.x + h4.w*w3.x;
        ay += h4.x*w0.y + h4.y*w1.y + h4.z*w2.y + h4.w*w3.y;
        az += h4.x*w0.z + h4.y*w1.z + h4.z*w2.z + h4.w*w3.z;
        aw += h4.x*w0.w + h4.y*w1.w + h4.z*w2.w + h4.w*w3.w;
      }
      float4 r = {ax+xw4.x, ay+xw4.y, az+xw4.z, aw+xw4.w};
      *((float4*)&gp[kk][q*4]) = r;
    }
    __syncthreads();
    if (t < H_) {
      float gi=0.f, gf=0.f, gg=0.f, go=0.f;
      #pragma unroll
      for (int m = 0; m < 5; ++m) {
        gi += gp[m][t]; gf += gp[m][H_+t]; gg += gp[m][2*H_+t]; go += gp[m][3*H_+t];
      }
      float ig = 1.f/(1.f+expf(-gi));
      float fg = 1.f/(1.f+expf(-gf));
      float og = 1.f/(1.f+expf(-go));
      c_j = fg*c_j + ig*tanhf(gg);
      float hn = og*tanhf(c_j);
      int pos = dir ? (len-1-step) : step;   // backward writes un-reversed position
      hout[((size_t)b*S_ + pos)*H_ + t] = hn;
      sh[t] = hn;
    }
    __syncthreads();
  }
}

// -------- scores: theta[b,head,s] = mask ? 1000 * h . wkq[:,head] : -1e9 --------
__global__ __launch_bounds__(256) void k_scores(
    const float* __restrict__ hf, const float* __restrict__ hb,
    const float* __restrict__ wkq, const int* __restrict__ lengths,
    float* __restrict__ theta)
{
  int wid = blockIdx.x*4 + (threadIdx.x >> 6);
  int lane = threadIdx.x & 63;
  int b = wid >> 9, s = wid & 511;
  const float* hfr = hf + ((size_t)b*S_ + s)*H_;
  const float* hbr = hb + ((size_t)b*S_ + s)*H_;
  float a0=0.f, a1=0.f, a2=0.f, a3=0.f;
  for (int e = lane; e < ENC_; e += 64) {
    float hv = (e < H_) ? hfr[e] : hbr[e-H_];
    float4 w = *(const float4*)(wkq + e*4);
    a0 += hv*w.x; a1 += hv*w.y; a2 += hv*w.z; a3 += hv*w.w;
  }
  for (int off = 32; off; off >>= 1) {
    a0 += __shfl_xor(a0, off); a1 += __shfl_xor(a1, off);
    a2 += __shfl_xor(a2, off); a3 += __shfl_xor(a3, off);
  }
  if (lane == 0) {
    bool valid = s < lengths[b];
    size_t base = (size_t)b*2048 + s;
    theta[base       ] = valid ? SCALE_*a0 : NEGV;
    theta[base +  512] = valid ? SCALE_*a1 : NEGV;
    theta[base + 1024] = valid ? SCALE_*a2 : NEGV;
    theta[base + 1536] = valid ? SCALE_*a3 : NEGV;
  }
}

// -------- sparseMAP budget projection, exact reference semantics, 1 wave / (b,head) --------
__global__ void k_sparsemap(const float* __restrict__ theta, const int* __restrict__ lengths,
                            float* __restrict__ mu) {
  int pid = blockIdx.x;
  int lane = threadIdx.x;
  const float* th = theta + (size_t)pid*512;
  float v[8];
  #pragma unroll
  for (int i = 0; i < 8; ++i) v[i] = th[i*64 + lane];
  float kf = rintf(0.2f * (float)lengths[pid >> 2]);   // jnp.round(0.2f*len), half-to-even
  float mn = v[0], mx = v[0];
  #pragma unroll
  for (int i = 1; i < 8; ++i) { mn = fminf(mn, v[i]); mx = fmaxf(mx, v[i]); }
  for (int off = 32; off; off >>= 1) {
    mn = fminf(mn, __shfl_xor(mn, off)); mx = fmaxf(mx, __shfl_xor(mx, off));
  }
  float lo = mn - 1.f, hi = mx;
  for (int it = 0; it < 60; ++it) {
    float mid = 0.5f*(lo + hi);
    float s = 0.f;
    #pragma unroll
    for (int i = 0; i < 8; ++i) s += fminf(fmaxf(v[i]-mid, 0.f), 1.f);
    for (int off = 32; off; off >>= 1) s += __shfl_xor(s, off);
    bool big = s > kf;
    lo = big ? mid : lo;
    hi = big ? hi : mid;
  }
  float tau0 = 0.5f*(lo + hi);
  float fs = 0.f, nU = 0.f, nS = 0.f;
  #pragma unroll
  for (int i = 0; i < 8; ++i) {
    float m0 = v[i] - tau0;
    if (m0 >= 1.f) nU += 1.f;
    else if (m0 > 0.f) { fs += v[i]; nS += 1.f; }
  }
  for (int off = 32; off; off >>= 1) {
    fs += __shfl_xor(fs, off); nU += __shfl_xor(nU, off); nS += __shfl_xor(nS, off);
  }
  float tau = (fs + nU - kf) / fmaxf(nS, 1.f);
  tau = (nS > 0.f) ? tau : tau0;
  float* mo = mu + (size_t)pid*512;
  #pragma unroll
  for (int i = 0; i < 8; ++i) mo[i*64 + lane] = fminf(fmaxf(v[i]-tau, 0.f), 1.f);
}

// -------- hp[b,head,e] = sum_s mu[b,head,s] * h[b,s,e]  (sparse: skip mu==0) --------
__global__ __launch_bounds__(512) void k_hp(
    const float* __restrict__ mu, const float* __restrict__ hf,
    const float* __restrict__ hb, float* __restrict__ hp)
{
  __shared__ float mul[512];
  int pid = blockIdx.x, b = pid >> 2;
  int t = threadIdx.x;
  mul[t] = mu[(size_t)pid*512 + t];
  __syncthreads();
  if (t < ENC_) {
    const float* hsrc = (t < H_) ? (hf + t) : (hb + (t - H_));
    float acc = 0.f;
    for (int s = 0; s < 512; ++s) {
      float m = mul[s];
      if (m != 0.f) acc += m * hsrc[((size_t)b*S_ + s)*H_];
    }
    hp[(size_t)pid*ENC_ + t] = acc;
  }
}

// -------- head: pp = hp @ Wv (per-head cols), pooled = pp @ W_out, y = sigmoid(pooled@W_head+b) --------
__global__ __launch_bounds__(512) void k_head(
    const float* __restrict__ hp, const float* __restrict__ Wv,
    const float* __restrict__ Wout, const float* __restrict__ Wh,
    const float* __restrict__ bh, float* __restrict__ out)
{
  __shared__ float hpl[1600];
  __shared__ float ppl[ENC_];
  __shared__ float ojl[ENC_];
  __shared__ float red[512];
  int b = blockIdx.x, t = threadIdx.x;
  for (int i = t; i < 1600; i += 512) hpl[i] = hp[(size_t)b*1600 + i];
  __syncthreads();
  if (t < ENC_) {
    int head = t / 100;
    float acc = 0.f;
    for (int e = 0; e < ENC_; ++e) acc += hpl[head*ENC_ + e] * Wv[(size_t)e*ENC_ + t];
    ppl[t] = acc;
  }
  __syncthreads();
  if (t < ENC_) {
    float acc = 0.f;
    for (int c = 0; c < ENC_; ++c) acc += ppl[c] * Wout[(size_t)c*ENC_ + t];
    ojl[t] = acc;
  }
  __syncthreads();
  red[t] = (t < ENC_) ? ojl[t]*Wh[t] : 0.f;
  __syncthreads();
  for (int sft = 256; sft; sft >>= 1) {
    if (t < sft) red[t] += red[t+sft];
    __syncthreads();
  }
  if (t == 0) out[b] = 1.f/(1.f + expf(-(red[0] + bh[0])));
}

// -------- z[b,s] = mask ? mean_head(mu) : 0 --------
__global__ void k_z(const float* __restrict__ mu, const int* __restrict__ lengths,
                    float* __restrict__ out) {
  int idx = blockIdx.x*256 + threadIdx.x;
  int b = idx >> 9, s = idx & 511;
  float zz = 0.f;
  if (s < lengths[b]) {
    size_t base = (size_t)b*2048 + s;
    zz = 0.25f*(mu[base] + mu[base+512] + mu[base+1024] + mu[base+1536]);
  }
  out[32 + idx] = zz;
}

extern "C" void kernel_launch(void* const* d_in, const int* in_sizes, int n_in,
                              void* d_out, int out_size, void* d_ws, size_t ws_size,
                              hipStream_t stream) {
  const int*   x    = (const int*)d_in[0];
  const void*  mask = d_in[1];
  const float* emb  = (const float*)d_in[2];
  const float* wihf = (const float*)d_in[3];
  const float* whhf = (const float*)d_in[4];
  const float* bf   = (const float*)d_in[5];
  const float* wihb = (const float*)d_in[6];
  const float* whhb = (const float*)d_in[7];
  const float* bb   = (const float*)d_in[8];
  const float* qs   = (const float*)d_in[9];
  const float* Wq   = (const float*)d_in[10];
  const float* Wk   = (const float*)d_in[11];
  const float* Wv   = (const float*)d_in[12];
  const float* Wout = (const float*)d_in[13];
  const float* Wh   = (const float*)d_in[14];
  const float* bh   = (const float*)d_in[15];
  float* out = (float*)d_out;
  float* W = (float*)d_ws;      // needs ~127 MiB of workspace
  int* lengths = (int*)(W + OF_LEN);

  k_lengths<<<32, 64, 0, stream>>>(mask, lengths);
  k_transpose<<<104, 256, 0, stream>>>(whhf, whhb, W+OF_WTF, W+OF_WTB);
  k_qvec<<<1, 512, 0, stream>>>(qs, Wq, W+OF_QVEC);
  k_wkq<<<7, 256, 0, stream>>>(Wk, W+OF_QVEC, W+OF_WKQ);
  hipMemsetAsync(W+OF_HF, 0, (size_t)B_*S_*H_*sizeof(float), stream);
  hipMemsetAsync(W+OF_HB, 0, (size_t)B_*S_*H_*sizeof(float), stream);
  k_gemm_in<<<dim3(128, 25), 256, 0, stream>>>(x, emb, wihf, wihb, bf, bb,
                                               W+OF_XWF, W+OF_XWB);
  k_lstm<<<64, 1024, 0, stream>>>(W+OF_XWF, W+OF_XWB, W+OF_WTF, W+OF_WTB,
                                  lengths, W+OF_HF, W+OF_HB);
  k_scores<<<4096, 256, 0, stream>>>(W+OF_HF, W+OF_HB, W+OF_WKQ, lengths, W+OF_THETA);
  k_sparsemap<<<128, 64, 0, stream>>>(W+OF_THETA, lengths, W+OF_MU);
  k_hp<<<128, 512, 0, stream>>>(W+OF_MU, W+OF_HF, W+OF_HB, W+OF_HP);
  k_head<<<32, 512, 0, stream>>>(W+OF_HP, Wv, Wout, Wh, bh, out);
  k_z<<<64, 256, 0, stream>>>(W+OF_MU, lengths, out);
}